// Round 1
// baseline (3884.685 us; speedup 1.0000x reference)
//
#include <hip/hip_runtime.h>

// Problem constants (fixed by the reference): B=64, T=512, D=1024, R=1024, O=1024
#define BB 64
#define TT 512
#define DD 1024
#define RR 1024

#define NBLK 64                 // scan blocks; block g owns h-cols [16g, 16g+16)
#define WST 1032                // LDS row stride in bf16 elems (1024 + 8 pad -> 2-way banks, free)
#define SCAN_LDS_BYTES (64 * WST * 2)   // 132096: epilogue stages full h; main loop uses 32 rows
#define SCRATCH_OFF (32 * WST * 2)      // 66048: per-wave 512B publish-pack scratch above weights

typedef __bf16 bf16x8 __attribute__((ext_vector_type(8)));
typedef float f32x4 __attribute__((ext_vector_type(4)));
typedef unsigned short us4 __attribute__((ext_vector_type(4)));
typedef unsigned int u32x4 __attribute__((ext_vector_type(4)));
typedef unsigned int u32x2 __attribute__((ext_vector_type(2)));

__device__ inline unsigned short f2bf(float f) {
  unsigned int u = __float_as_uint(f);
  u = (u + 0x7fffu + ((u >> 16) & 1u)) >> 16;   // RNE
  return (unsigned short)u;
}
__device__ inline float bf2f(unsigned short b) {
  return __uint_as_float(((unsigned int)b) << 16);
}

// Coherent 16B load: bypasses L1/L2 (sc0 sc1), served by the coherence point.
// Caller must s_waitcnt vmcnt(N) (via asm) before using the result.
__device__ inline u32x4 ld16_sc(const void* p) {
  u32x4 r;
  asm volatile("global_load_dwordx4 %0, %1, off sc0 sc1"
               : "=v"(r) : "v"(p) : "memory");
  return r;
}
// Coherent 8B store (device-visible, pairs with ld16_sc readers).
__device__ inline void st8_sc(void* p, u32x2 v) {
  asm volatile("global_store_dwordx2 %0, %1, off sc0 sc1"
               :: "v"(p), "v"(v) : "memory");
}

// issue 8 coherent 16B loads at stride 64B (one MFMA K-chunk of a 16-row A panel)
__device__ inline void issue8(u32x4* d, const char* base) {
#pragma unroll
  for (int i = 0; i < 8; ++i) d[i] = ld16_sc(base + (size_t)i * 64);
}

// ---- fp32 -> bf16 vectorized convert (n4 = n/4 groups) ----
__global__ void k_f2b4(const float* __restrict__ in, unsigned short* __restrict__ out, int n4) {
  int i = blockIdx.x * blockDim.x + threadIdx.x;
  if (i < n4) {
    const float4 v = ((const float4*)in)[i];
    us4 o;
    o.x = f2bf(v.x); o.y = f2bf(v.y); o.z = f2bf(v.z); o.w = f2bf(v.w);
    ((us4*)out)[i] = o;
  }
}

// ---- transpose 1024x1024 fp32 -> bf16 (out[j][k] = in[k][j]) ----
__global__ __launch_bounds__(256) void k_transpose_bf16(
    const float* __restrict__ in, unsigned short* __restrict__ out) {
  __shared__ float tile[32][33];
  const int bx = blockIdx.x * 32, by0 = blockIdx.y * 32;
  const int tx = threadIdx.x, ty = threadIdx.y;  // block (32,8)
#pragma unroll
  for (int r = 0; r < 32; r += 8)
    tile[ty + r][tx] = in[(size_t)(by0 + ty + r) * 1024 + bx + tx];
  __syncthreads();
#pragma unroll
  for (int r = 0; r < 32; r += 8)
    out[(size_t)(bx + ty + r) * 1024 + by0 + tx] = f2bf(tile[tx][ty + r]);
}

// ---- async global->LDS, 16B per lane ----
__device__ inline void gload_lds16(const unsigned short* g, unsigned short* l) {
  __builtin_amdgcn_global_load_lds(
      (const __attribute__((address_space(1))) unsigned int*)g,
      (__attribute__((address_space(3))) unsigned int*)l, 16, 0, 0);
}

// ---- bf16 GEMM, C[m,n] = sum_k A[m,k]*B[n,k], 128x128 tile, BK=32 ----
// EPI==0: out = xhz time-major [T][B][2048] bf16, bias folded (bh n<1024, bz else)
// EPI==1: out[m*1024+n] bf16 (Mz into Wrec rows 1024..2047)
template <int EPI>
__global__ __launch_bounds__(256) void gemm_bt(
    const unsigned short* __restrict__ A,
    const unsigned short* __restrict__ Bm,
    const float* __restrict__ bias_h,
    const float* __restrict__ bias_z,
    unsigned short* __restrict__ outb, int K) {
  __shared__ __attribute__((aligned(16))) unsigned short As[128 * 32];
  __shared__ __attribute__((aligned(16))) unsigned short Bs[128 * 32];
  const int tid = threadIdx.x;
  const int m0 = blockIdx.y * 128, n0 = blockIdx.x * 128;
  const int lane = tid & 63, wid = tid >> 6;
  const int l16 = lane & 15, quad = lane >> 4;
  const int wm = (wid & 1) * 64, wn = (wid >> 1) * 64;

  f32x4 acc[4][4] = {};

  const int c0 = tid, c1 = 256 + tid;
  const int rowA0 = c0 >> 2, colA0 = (c0 & 3) << 3;
  const int rowA1 = c1 >> 2, colA1 = (c1 & 3) << 3;

  for (int kk = 0; kk < K; kk += 32) {
    __syncthreads();
    gload_lds16(A + (size_t)(m0 + rowA0) * K + kk + colA0, As + c0 * 8);
    gload_lds16(A + (size_t)(m0 + rowA1) * K + kk + colA1, As + c1 * 8);
    gload_lds16(Bm + (size_t)(n0 + rowA0) * K + kk + colA0, Bs + c0 * 8);
    gload_lds16(Bm + (size_t)(n0 + rowA1) * K + kk + colA1, Bs + c1 * 8);
    __syncthreads();
    bf16x8 af[4], bfr[4];
#pragma unroll
    for (int i = 0; i < 4; ++i) {
      af[i] = *(const bf16x8*)&As[(wm + i * 16 + l16) * 32 + quad * 8];
      bfr[i] = *(const bf16x8*)&Bs[(wn + i * 16 + l16) * 32 + quad * 8];
    }
#pragma unroll
    for (int i = 0; i < 4; ++i)
#pragma unroll
      for (int j = 0; j < 4; ++j)
        acc[i][j] = __builtin_amdgcn_mfma_f32_16x16x32_bf16(af[i], bfr[j], acc[i][j], 0, 0, 0);
  }

#pragma unroll
  for (int i = 0; i < 4; ++i) {
#pragma unroll
    for (int j = 0; j < 4; ++j) {
#pragma unroll
      for (int r = 0; r < 4; ++r) {
        const int m = m0 + wm + i * 16 + quad * 4 + r;
        const int n = n0 + wn + j * 16 + l16;
        float v = acc[i][j][r];
        if (EPI == 0) {
          v += (n < 1024) ? bias_h[n] : bias_z[n - 1024];
          const int b = m >> 9;          // m = b*T + t, T=512
          const int t = m & 511;
          outb[((size_t)(t * 64 + b) << 11) + n] = f2bf(v);
        } else {
          outb[(size_t)m * 1024 + n] = f2bf(v);
        }
      }
    }
  }
}

// ---- persistent scan over T=512 steps + output GEMM ----
// 64 blocks x 256 threads (4 waves, one per SIMD). Block g owns h-cols
// [g*16, g*16+16). Its 32 MFMA n-cols (16 Whh rows + 16 Mz rows, 64 KB bf16)
// are LDS-resident for the whole scan. Each wave rg computes FULL-K
// (M=16 batch rows rg*16.., N=16h+16z, K=1024): the accumulator is final —
// no K-split, no LDS reduction, no staging bounce, one __syncthreads/step.
// A-fragments are loaded straight from the coherence point (sc0 sc1) into
// registers, 2 chunks ahead, counted vmcnt(16/8/0). Elementwise gate update
// is in-wave (h- and z-partials share a lane); h' repacked via a 512B
// per-wave LDS scratch into 8B coherent stores. Flag barrier protocol kept
// from the r3-validated kernel (vmcnt-drain -> syncthreads -> relaxed flag).
__global__ __launch_bounds__(256, 1) void scan_out_k(
    const unsigned short* __restrict__ xhz,   // [T][B][2048] bf16
    const unsigned short* __restrict__ Wrec,  // [2048][1024] bf16 (Whh ; Mz)
    const unsigned short* __restrict__ Wyb,   // [1024][1024] bf16
    const float* __restrict__ by,
    unsigned short* __restrict__ hb0, unsigned short* __restrict__ hb1,
    unsigned int* __restrict__ flags,
    float* __restrict__ out) {
  extern __shared__ char smem[];
  unsigned short* wlds = (unsigned short*)smem;   // [32][WST] weights (main loop) / [64][WST] h (epilogue)

  const int tid = threadIdx.x, g = blockIdx.x;
  const int lane = tid & 63, rg = tid >> 6;       // rg = wave id = batch-row group
  const int l16 = lane & 15, quad = lane >> 4;

  // ---- prologue: stage this block's 32 weight rows into LDS ----
  {
    const int row = tid >> 3, seg = tid & 7;      // 32 rows x 8 segs x 256B
    const unsigned short* src = (row < 16)
        ? Wrec + ((size_t)(g * 16 + row) << 10)
        : Wrec + ((size_t)(1024 + g * 16 + (row - 16)) << 10);
    src += seg * 128;
    unsigned short* dst = wlds + row * WST + seg * 128;
#pragma unroll
    for (int i = 0; i < 16; ++i)
      *(u32x4*)(dst + i * 8) = *(const u32x4*)(src + i * 8);
  }
  __syncthreads();

  // per-lane invariants
  const size_t abase = ((size_t)(rg * 16 + l16) << 11) + quad * 16;  // byte off in h buf
  const unsigned short* wh = wlds + (size_t)l16 * WST + quad * 8;          // Whh frag base
  const unsigned short* wz = wlds + (size_t)(16 + l16) * WST + quad * 8;   // Mz frag base
  char* scratch = smem + SCRATCH_OFF + rg * 512;
  const int b_ew = rg * 16 + quad * 4;            // first batch row (elementwise)
  const int col = g * 16 + l16;                   // owned h-col
  const size_t pub_off = ((size_t)(rg * 16 + (lane >> 2)) << 11) + g * 32 + (lane & 3) * 8;

  float hold[4] = {0.f, 0.f, 0.f, 0.f};           // fp32 master h, register-resident

  for (int tt = 0; tt < TT; ++tt) {
    // ---- xhz prefetch (independent of barrier; drained during poll) ----
    unsigned short xh[4], xz[4];
    {
      const size_t xb = ((size_t)(tt * 64 + b_ew)) << 11;
#pragma unroll
      for (int r = 0; r < 4; ++r) {
        xh[r] = xhz[xb + ((size_t)r << 11) + col];
        xz[r] = xhz[xb + ((size_t)r << 11) + 1024 + col];
      }
    }
    // ---- poll: all producers published step tt's input (flags >= tt) ----
    {
      const unsigned int tgt = (unsigned int)tt;
      unsigned int v;
      do {
        v = __hip_atomic_load(&flags[lane], __ATOMIC_RELAXED, __HIP_MEMORY_SCOPE_AGENT);
      } while (__any(v < tgt));
    }

    const char* hb = (tt & 1) ? (const char*)hb1 : (const char*)hb0;
    unsigned short* hd = (tt & 1) ? hb0 : hb1;

    // ---- full-K MFMA, A from coherence point, 2 chunks ahead ----
    u32x4 tbuf[4][8];
    issue8(tbuf[0], hb + abase);
    issue8(tbuf[1], hb + abase + 512);
    f32x4 acc0 = {0.f, 0.f, 0.f, 0.f};
    f32x4 acc1 = {0.f, 0.f, 0.f, 0.f};
#pragma unroll
    for (int c = 0; c < 4; ++c) {
      if (c < 2) issue8(tbuf[c + 2], hb + abase + (size_t)(c + 2) * 512);
      if (c < 2)       asm volatile("s_waitcnt vmcnt(16)" ::: "memory");
      else if (c == 2) asm volatile("s_waitcnt vmcnt(8)" ::: "memory");
      else             asm volatile("s_waitcnt vmcnt(0)" ::: "memory");
      __builtin_amdgcn_sched_barrier(0);
#pragma unroll
      for (int i = 0; i < 8; ++i) {
        const int kk = c * 8 + i;
        const bf16x8 a = __builtin_bit_cast(bf16x8, tbuf[c][i]);
        acc0 = __builtin_amdgcn_mfma_f32_16x16x32_bf16(a, *(const bf16x8*)(wh + kk * 32), acc0, 0, 0, 0);
        acc1 = __builtin_amdgcn_mfma_f32_16x16x32_bf16(a, *(const bf16x8*)(wz + kk * 32), acc1, 0, 0, 0);
      }
    }

    // ---- elementwise gate update, fully in-wave ----
    unsigned short hp[4];
#pragma unroll
    for (int r = 0; r < 4; ++r) {
      const float xhf = bf2f(xh[r]), xzf = bf2f(xz[r]);
      const float z = 1.0f / (1.0f + __expf(-(xzf + acc1[r])));
      const float hbv = fmaxf(xhf + acc0[r], 0.0f);
      hold[r] = z * hold[r] + (1.0f - z) * hbv;
      hp[r] = f2bf(hold[r]);
    }
    // pack 16x16 bf16 tile via per-wave scratch -> coalesced 8B coherent stores
#pragma unroll
    for (int r = 0; r < 4; ++r)
      ((unsigned short*)scratch)[(quad * 4 + r) * 16 + l16] = hp[r];
    asm volatile("s_waitcnt lgkmcnt(0)" ::: "memory");
    __builtin_amdgcn_sched_barrier(0);
    const u32x2 pv = *(const u32x2*)(scratch + lane * 8);
    st8_sc((char*)hd + pub_off, pv);

    // ---- publish -> flag (validated fence-free protocol) ----
    asm volatile("s_waitcnt vmcnt(0)" ::: "memory");
    __syncthreads();
    if (tid == 0)
      __hip_atomic_store(&flags[g], (unsigned int)(tt + 1),
                         __ATOMIC_RELAXED, __HIP_MEMORY_SCOPE_AGENT);
  }

  // ---- epilogue: out = h_final @ Wy^T + by ----
  {
    unsigned int v;
    do {
      v = __hip_atomic_load(&flags[lane], __ATOMIC_RELAXED, __HIP_MEMORY_SCOPE_AGENT);
    } while (__any(v < (unsigned int)TT));
  }
  __syncthreads();
  // stage final h (hb0: T even) into LDS [64][WST], overwriting weights
  {
    const char* hfin = (const char*)hb0;
    const int row = tid >> 2, seg = tid & 3;      // 64 rows x 4 segs x 512B
    const size_t gb = ((size_t)row << 11) + seg * 512;
    unsigned short* dst = wlds + (size_t)row * WST + seg * 256;
#pragma unroll
    for (int c = 0; c < 4; ++c) {
      u32x4 t4[8];
#pragma unroll
      for (int i = 0; i < 8; ++i) t4[i] = ld16_sc(hfin + gb + (size_t)(c * 8 + i) * 16);
      asm volatile("s_waitcnt vmcnt(0)" ::: "memory");
      __builtin_amdgcn_sched_barrier(0);
#pragma unroll
      for (int i = 0; i < 8; ++i) *(u32x4*)(dst + (c * 8 + i) * 8) = t4[i];
    }
  }
  __syncthreads();
  {
    const unsigned short* a_l = wlds + (size_t)(rg * 16 + l16) * WST + quad * 8;
    const unsigned short* byw = Wyb + ((size_t)col << 10) + quad * 8;
    f32x4 acc = {0.f, 0.f, 0.f, 0.f};
#pragma unroll
    for (int kk = 0; kk < 32; ++kk) {
      const bf16x8 a = *(const bf16x8*)(a_l + kk * 32);
      const bf16x8 b = *(const bf16x8*)(byw + kk * 32);
      acc = __builtin_amdgcn_mfma_f32_16x16x32_bf16(a, b, acc, 0, 0, 0);
    }
    const float bias = by[col];
#pragma unroll
    for (int r = 0; r < 4; ++r)
      out[((size_t)(rg * 16 + quad * 4 + r) << 10) + col] = acc[r] + bias;
  }
}

extern "C" void kernel_launch(void* const* d_in, const int* in_sizes, int n_in,
                              void* d_out, int out_size, void* d_ws, size_t ws_size,
                              hipStream_t stream) {
  const float* x = (const float*)d_in[0];
  const float* Wxh = (const float*)d_in[1];
  const float* bh = (const float*)d_in[2];
  const float* Whh = (const float*)d_in[3];
  const float* Wxz = (const float*)d_in[4];
  const float* bz = (const float*)d_in[5];
  const float* Whz = (const float*)d_in[6];
  const float* Wy = (const float*)d_in[7];
  const float* by = (const float*)d_in[8];
  float* out = (float*)d_out;

  char* ws = (char*)d_ws;
  size_t off = 0;
  auto alloc = [&](size_t bytes) -> void* {
    void* p = ws + off;
    off += (bytes + 255) & ~(size_t)255;
    return p;
  };
  const size_t nX = (size_t)BB * TT * DD;  // 33554432
  unsigned short* xb = (unsigned short*)alloc(nX * 2);                  // x bf16
  unsigned short* Wcat = (unsigned short*)alloc((size_t)2048 * 1024 * 2);  // [Wxh;Wxz]
  unsigned short* WhzT = (unsigned short*)alloc((size_t)1024 * 1024 * 2);  // Whz^T
  unsigned short* Wrec = (unsigned short*)alloc((size_t)2048 * 1024 * 2);  // [Whh;Mz]
  unsigned short* Wyb = (unsigned short*)alloc((size_t)1024 * 1024 * 2);   // Wy bf16
  unsigned short* xhz = (unsigned short*)alloc((size_t)TT * BB * 2048 * 2);  // 128 MB
  unsigned short* hb0 = (unsigned short*)alloc((size_t)BB * RR * 2);
  unsigned short* hb1 = (unsigned short*)alloc((size_t)BB * RR * 2);
  unsigned int* flags = (unsigned int*)alloc(1024);

  hipMemsetAsync(hb0, 0, (size_t)BB * RR * 2, stream);
  hipMemsetAsync(flags, 0, 1024, stream);

  // weight / input conversions
  k_f2b4<<<dim3((unsigned)(nX / 4 / 256)), 256, 0, stream>>>(x, xb, (int)(nX / 4));
  k_f2b4<<<dim3(1024), 256, 0, stream>>>(Wxh, Wcat, 262144);
  k_f2b4<<<dim3(1024), 256, 0, stream>>>(Wxz, Wcat + 1024 * 1024, 262144);
  k_f2b4<<<dim3(1024), 256, 0, stream>>>(Whh, Wrec, 262144);
  k_f2b4<<<dim3(1024), 256, 0, stream>>>(Wy, Wyb, 262144);
  k_transpose_bf16<<<dim3(32, 32), dim3(32, 8), 0, stream>>>(Whz, WhzT);

  // Mz = Wxz @ Whz  -> Wrec rows 1024..2047
  gemm_bt<1><<<dim3(8, 8), 256, 0, stream>>>(Wcat + 1024 * 1024, WhzT, nullptr, nullptr,
                                             Wrec + (size_t)1024 * 1024, 1024);
  // xhz = x @ [Wxh;Wxz]^T + [bh;bz], time-major
  gemm_bt<0><<<dim3(16, 256), 256, 0, stream>>>(xb, Wcat, bh, bz, xhz, 1024);

  // cooperative launch; opt in to 129 KB dynamic LDS (idempotent, capture-safe)
  hipFuncSetAttribute((const void*)scan_out_k,
                      hipFuncAttributeMaxDynamicSharedMemorySize, SCAN_LDS_BYTES);
  const unsigned short* xhz_c = xhz;
  const unsigned short* Wrec_c = Wrec;
  const unsigned short* Wyb_c = Wyb;
  const float* by_c = by;
  void* kargs[] = {(void*)&xhz_c, (void*)&Wrec_c, (void*)&Wyb_c, (void*)&by_c,
                   (void*)&hb0, (void*)&hb1, (void*)&flags, (void*)&out};
  hipLaunchCooperativeKernel((void*)scan_out_k, dim3(NBLK), dim3(256),
                             kargs, SCAN_LDS_BYTES, stream);
}

// Round 3
// 3528.854 us; speedup vs baseline: 1.1008x; 1.1008x over previous
//
#include <hip/hip_runtime.h>

// Problem constants (fixed by the reference): B=64, T=512, D=1024, R=1024, O=1024
#define BB 64
#define TT 512
#define DD 1024
#define RR 1024

#define SCAN_BLOCKS 32
#define HS_STRIDE 1032            // staged h row stride in bf16 (1024 + 8 pad)
#define SCAN_LDS_BYTES (64 * HS_STRIDE * 2)   // 132096; red overlay needs 69632
#define SLOT_BYTES (BB * RR * 2)  // 131072: one h ring slot (64 x 1024 bf16)

typedef __bf16 bf16x8 __attribute__((ext_vector_type(8)));
typedef float f32x4 __attribute__((ext_vector_type(4)));
typedef unsigned short us4 __attribute__((ext_vector_type(4)));
typedef unsigned int u32x4 __attribute__((ext_vector_type(4)));

__device__ inline unsigned short f2bf(float f) {
  unsigned int u = __float_as_uint(f);
  u = (u + 0x7fffu + ((u >> 16) & 1u)) >> 16;   // RNE
  return (unsigned short)u;
}
__device__ inline float bf2f(unsigned short b) {
  return __uint_as_float(((unsigned int)b) << 16);
}

// Coherent 16B load: bypasses L1/L2 (sc0 sc1), served by the coherence point.
// Caller must s_waitcnt vmcnt(0) (via asm) before using the result.
__device__ inline u32x4 ld16_sc(const void* p) {
  u32x4 r;
  asm volatile("global_load_dwordx4 %0, %1, off sc0 sc1"
               : "=v"(r) : "v"(p) : "memory");
  return r;
}
// Coherent 4B store (device-visible; one packed bf16 pair = one dword: the
// sentinel protocol's atomicity granule).
__device__ inline void st4_sc(void* p, unsigned int v) {
  asm volatile("global_store_dword %0, %1, off sc0 sc1"
               :: "v"(p), "v"(v) : "memory");
}

// ---- fp32 -> bf16 vectorized convert (n4 = n/4 groups) ----
__global__ void k_f2b4(const float* __restrict__ in, unsigned short* __restrict__ out, int n4) {
  int i = blockIdx.x * blockDim.x + threadIdx.x;
  if (i < n4) {
    const float4 v = ((const float4*)in)[i];
    us4 o;
    o.x = f2bf(v.x); o.y = f2bf(v.y); o.z = f2bf(v.z); o.w = f2bf(v.w);
    ((us4*)out)[i] = o;
  }
}

// ---- transpose 1024x1024 fp32 -> bf16 (out[j][k] = in[k][j]) ----
__global__ __launch_bounds__(256) void k_transpose_bf16(
    const float* __restrict__ in, unsigned short* __restrict__ out) {
  __shared__ float tile[32][33];
  const int bx = blockIdx.x * 32, by0 = blockIdx.y * 32;
  const int tx = threadIdx.x, ty = threadIdx.y;  // block (32,8)
#pragma unroll
  for (int r = 0; r < 32; r += 8)
    tile[ty + r][tx] = in[(size_t)(by0 + ty + r) * 1024 + bx + tx];
  __syncthreads();
#pragma unroll
  for (int r = 0; r < 32; r += 8)
    out[(size_t)(bx + ty + r) * 1024 + by0 + tx] = f2bf(tile[tx][ty + r]);
}

// ---- async global->LDS, 16B per lane ----
__device__ inline void gload_lds16(const unsigned short* g, unsigned short* l) {
  __builtin_amdgcn_global_load_lds(
      (const __attribute__((address_space(1))) unsigned int*)g,
      (__attribute__((address_space(3))) unsigned int*)l, 16, 0, 0);
}

// ---- bf16 GEMM, C[m,n] = sum_k A[m,k]*B[n,k], 128x128 tile, BK=32 ----
// EPI==0: out = xhz time-major [T][B][2048] bf16, bias folded (bh n<1024, bz else)
// EPI==1: out[m*1024+n] bf16 (Mz into Wrec rows 1024..2047)
template <int EPI>
__global__ __launch_bounds__(256) void gemm_bt(
    const unsigned short* __restrict__ A,
    const unsigned short* __restrict__ Bm,
    const float* __restrict__ bias_h,
    const float* __restrict__ bias_z,
    unsigned short* __restrict__ outb, int K) {
  __shared__ __attribute__((aligned(16))) unsigned short As[128 * 32];
  __shared__ __attribute__((aligned(16))) unsigned short Bs[128 * 32];
  const int tid = threadIdx.x;
  const int m0 = blockIdx.y * 128, n0 = blockIdx.x * 128;
  const int lane = tid & 63, wid = tid >> 6;
  const int l16 = lane & 15, quad = lane >> 4;
  const int wm = (wid & 1) * 64, wn = (wid >> 1) * 64;

  f32x4 acc[4][4] = {};

  const int c0 = tid, c1 = 256 + tid;
  const int rowA0 = c0 >> 2, colA0 = (c0 & 3) << 3;
  const int rowA1 = c1 >> 2, colA1 = (c1 & 3) << 3;

  for (int kk = 0; kk < K; kk += 32) {
    __syncthreads();
    gload_lds16(A + (size_t)(m0 + rowA0) * K + kk + colA0, As + c0 * 8);
    gload_lds16(A + (size_t)(m0 + rowA1) * K + kk + colA1, As + c1 * 8);
    gload_lds16(Bm + (size_t)(n0 + rowA0) * K + kk + colA0, Bs + c0 * 8);
    gload_lds16(Bm + (size_t)(n0 + rowA1) * K + kk + colA1, Bs + c1 * 8);
    __syncthreads();
    bf16x8 af[4], bfr[4];
#pragma unroll
    for (int i = 0; i < 4; ++i) {
      af[i] = *(const bf16x8*)&As[(wm + i * 16 + l16) * 32 + quad * 8];
      bfr[i] = *(const bf16x8*)&Bs[(wn + i * 16 + l16) * 32 + quad * 8];
    }
#pragma unroll
    for (int i = 0; i < 4; ++i)
#pragma unroll
      for (int j = 0; j < 4; ++j)
        acc[i][j] = __builtin_amdgcn_mfma_f32_16x16x32_bf16(af[i], bfr[j], acc[i][j], 0, 0, 0);
  }

#pragma unroll
  for (int i = 0; i < 4; ++i) {
#pragma unroll
    for (int j = 0; j < 4; ++j) {
#pragma unroll
      for (int r = 0; r < 4; ++r) {
        const int m = m0 + wm + i * 16 + quad * 4 + r;
        const int n = n0 + wn + j * 16 + l16;
        float v = acc[i][j][r];
        if (EPI == 0) {
          v += (n < 1024) ? bias_h[n] : bias_z[n - 1024];
          const int b = m >> 9;          // m = b*T + t, T=512
          const int t = m & 511;
          outb[((size_t)(t * 64 + b) << 11) + n] = f2bf(v);
        } else {
          outb[(size_t)m * 1024 + n] = f2bf(v);
        }
      }
    }
  }
}

// ---- persistent scan over T=512 steps + output GEMM ----
// Round-0 validated structure (32 blocks x 1024 threads, LDS-staged h,
// 4-way K-split MFMA, LDS K-reduce, fp32 register-resident master h) with the
// flag barrier replaced by a POISON/SENTINEL ring protocol:
//   * 4-slot h ring; data(t) -> slot t&3; slots pre-poisoned with 0xFFFFFFFF
//     (two bf16 NaNs -- unreachable from f2bf of finite arithmetic).
//   * Producers publish h' (packed 4B dwords, sc0 sc1) and a poison store for
//     slot (t+2)&3, then proceed -- NO drain, NO flag, NO poll.
//   * Consumers validate every staged dword against the sentinel; poison =>
//     predicated retry. Freshness proof: a reader reaches iter v only after
//     validating data(v-2); each producer publishes data(v-2) only after its
//     poison of slot(v-1 .. ) was force-ACK'd by its head-of-iter vmcnt(0).
//     So slot reads return poison-or-fresh, never 4-steps-old data. WAR on
//     reuse is covered by the same induction (all blocks past iter t-1 reads
//     when anyone is at end of iter t).
// This deletes the store-drain RT and the flag RT+poll from the serial chain;
// the publish ACK now overlaps the next iteration's stage-load RT.
__global__ __launch_bounds__(1024) void scan_out_k(
    const unsigned short* __restrict__ xhz,   // [T][B][2048] bf16
    const unsigned short* __restrict__ Wrec,  // [2048][1024] bf16 (Whh ; Mz)
    const unsigned short* __restrict__ Wyb,   // [1024][1024] bf16
    const float* __restrict__ by,
    unsigned short* __restrict__ hring,       // 4 slots x [64][1024] bf16
    float* __restrict__ out) {
  extern __shared__ char smem[];
  unsigned short* hs = (unsigned short*)smem;   // staged h [64][HS_STRIDE]
  float* red = (float*)smem;                    // overlay: [4][64][68] f32

  const int tid = threadIdx.x, g = blockIdx.x;
  const int lane = tid & 63, wid = tid >> 6;
  const int l16 = lane & 15, quad = lane >> 4;
  const int ks = wid >> 2, nsub = wid & 3;
  const int kw = ks * 256;                      // wave's K slice (bf16 elems)
  const int i0 = g * 32;

  // loop-invariant B fragments: 16 n-cols x 256 k slice -> 32 VGPRs (cached)
  const int bcol = (nsub < 2) ? (i0 + nsub * 16 + l16)
                              : (1024 + i0 + (nsub - 2) * 16 + l16);
  const unsigned short* Bb = Wrec + (size_t)bcol * 1024 + kw + quad * 8;
  bf16x8 bfr[8];
#pragma unroll
  for (int s = 0; s < 8; ++s) bfr[s] = *(const bf16x8*)(Bb + s * 32);

  // staging coords: thread copies 8 x 16B chunks of row sr (stride 256B)
  const int sr = tid >> 4;          // h row (b) 0..63
  const int su = tid & 15;          // 16B unit within row
  const size_t srow = (size_t)sr * 2048 + su * 16;   // byte offset within a slot
  unsigned short* ldst = hs + sr * HS_STRIDE + su * 8;

  // elementwise coords: thread owns (b=eb, cols i0+ej, i0+ej+1)
  const int eb = tid >> 4, ej = (tid & 15) * 2;
  const size_t pub_elem = (size_t)eb * 1024 + i0 + ej;  // dword-aligned pair
  float hold0 = 0.0f, hold1 = 0.0f;   // fp32 master h, register-resident

  for (int tt = 0; tt < TT; ++tt) {
    const char* src = (const char*)hring + (size_t)((tt + 3) & 3) * SLOT_BYTES;
    char* dst = (char*)hring + (size_t)(tt & 3) * SLOT_BYTES;
    char* poi = (char*)hring + (size_t)((tt + 2) & 3) * SLOT_BYTES;

    // ---- stage h -> regs (16B coherent loads) + xhz prefetch ----
    u32x4 tmp[8];
#pragma unroll
    for (int c = 0; c < 8; ++c)
      tmp[c] = ld16_sc(src + srow + c * 256);
    const size_t xrow = ((size_t)(tt * 64 + eb)) << 11;
    const unsigned int xh2 = *(const unsigned int*)(xhz + xrow + i0 + ej);
    const unsigned int xz2 = *(const unsigned int*)(xhz + xrow + 1024 + i0 + ej);
    // drain: covers these loads AND the previous iteration's publish+poison
    // stores (ACK overlapped with the load round trip, not serialized).
    asm volatile("s_waitcnt vmcnt(0)" ::: "memory");
    __builtin_amdgcn_sched_barrier(0);

    // ---- sentinel validation + predicated retry ----
    unsigned int bad = 0;
#pragma unroll
    for (int c = 0; c < 8; ++c) {
      bool b = false;
#pragma unroll
      for (int i = 0; i < 4; ++i) b = b || (tmp[c][i] == 0xFFFFFFFFu);
      if (b) bad |= (1u << c);
    }
    while (__any(bad != 0)) {
#pragma unroll
      for (int c = 0; c < 8; ++c)
        if (bad & (1u << c)) tmp[c] = ld16_sc(src + srow + c * 256);
      asm volatile("s_waitcnt vmcnt(0)" ::: "memory");
      __builtin_amdgcn_sched_barrier(0);
      bad = 0;
#pragma unroll
      for (int c = 0; c < 8; ++c) {
        bool b = false;
#pragma unroll
        for (int i = 0; i < 4; ++i) b = b || (tmp[c][i] == 0xFFFFFFFFu);
        if (b) bad |= (1u << c);
      }
    }
#pragma unroll
    for (int c = 0; c < 8; ++c)
      *(u32x4*)(ldst + c * 128) = tmp[c];       // c*256 bytes
    __syncthreads();

    // ---- MFMA: acc[mt] over 64 b-rows, this wave's (ks, nsub) ----
    f32x4 acc[4] = {};
#pragma unroll
    for (int s = 0; s < 8; ++s) {
#pragma unroll
      for (int mt = 0; mt < 4; ++mt) {
        const bf16x8 afr = *(const bf16x8*)(hs + (mt * 16 + l16) * HS_STRIDE + kw + s * 32 + quad * 8);
        acc[mt] = __builtin_amdgcn_mfma_f32_16x16x32_bf16(afr, bfr[s], acc[mt], 0, 0, 0);
      }
    }
    __syncthreads();   // all ds_reads of hs done; safe to overlay red

    // ---- K-reduction partials into LDS ----
#pragma unroll
    for (int mt = 0; mt < 4; ++mt)
#pragma unroll
      for (int r = 0; r < 4; ++r)
        red[(size_t)(ks * 64 + mt * 16 + quad * 4 + r) * 68 + nsub * 16 + l16] = acc[mt][r];
    __syncthreads();

    // ---- elementwise update (all 1024 threads, 2 elems each) ----
    float ph0 = 0.f, ph1 = 0.f, pz0 = 0.f, pz1 = 0.f;
#pragma unroll
    for (int w = 0; w < 4; ++w) {
      const float* rb = red + (size_t)(w * 64 + eb) * 68;
      ph0 += rb[ej]; ph1 += rb[ej + 1];
      pz0 += rb[32 + ej]; pz1 += rb[32 + ej + 1];
    }
    {
      const float xh0 = bf2f((unsigned short)(xh2 & 0xffff));
      const float xh1 = bf2f((unsigned short)(xh2 >> 16));
      const float xz0 = bf2f((unsigned short)(xz2 & 0xffff));
      const float xz1 = bf2f((unsigned short)(xz2 >> 16));
      const float z0 = 1.0f / (1.0f + __expf(-(xz0 + pz0)));
      const float z1 = 1.0f / (1.0f + __expf(-(xz1 + pz1)));
      const float hb_0 = fmaxf(xh0 + ph0, 0.0f);
      const float hb_1 = fmaxf(xh1 + ph1, 0.0f);
      hold0 = z0 * hold0 + (1.0f - z0) * hb_0;
      hold1 = z1 * hold1 + (1.0f - z1) * hb_1;
      const unsigned int pk = (unsigned int)f2bf(hold0) | ((unsigned int)f2bf(hold1) << 16);
      // publish h'(t) and poison slot (t+2)&3 -- no drain, no flag.
      st4_sc(dst + pub_elem * 2, pk);
      st4_sc(poi + pub_elem * 2, 0xFFFFFFFFu);
    }
    // one barrier: red-overlay reads done before next iter's hs ds_writes
    __syncthreads();
  }

  // ---- epilogue: out = h_final @ Wy^T + by ----
  // h_final = data(511) in slot 3; stage with the same validation.
  {
    const char* src = (const char*)hring + (size_t)3 * SLOT_BYTES;
    u32x4 tmp[8];
#pragma unroll
    for (int c = 0; c < 8; ++c)
      tmp[c] = ld16_sc(src + srow + c * 256);
    asm volatile("s_waitcnt vmcnt(0)" ::: "memory");
    __builtin_amdgcn_sched_barrier(0);
    unsigned int bad = 0;
#pragma unroll
    for (int c = 0; c < 8; ++c) {
      bool b = false;
#pragma unroll
      for (int i = 0; i < 4; ++i) b = b || (tmp[c][i] == 0xFFFFFFFFu);
      if (b) bad |= (1u << c);
    }
    while (__any(bad != 0)) {
#pragma unroll
      for (int c = 0; c < 8; ++c)
        if (bad & (1u << c)) tmp[c] = ld16_sc(src + srow + c * 256);
      asm volatile("s_waitcnt vmcnt(0)" ::: "memory");
      __builtin_amdgcn_sched_barrier(0);
      bad = 0;
#pragma unroll
      for (int c = 0; c < 8; ++c) {
        bool b = false;
#pragma unroll
        for (int i = 0; i < 4; ++i) b = b || (tmp[c][i] == 0xFFFFFFFFu);
        if (b) bad |= (1u << c);
      }
    }
#pragma unroll
    for (int c = 0; c < 8; ++c)
      *(u32x4*)(ldst + c * 128) = tmp[c];
  }
  __syncthreads();

  if (nsub < 2) {   // 8 waves compute the block's 32 out-cols
    const int ocol = i0 + nsub * 16 + l16;
    const unsigned short* Byb = Wyb + (size_t)ocol * 1024 + kw + quad * 8;
    f32x4 acc[4] = {};
#pragma unroll
    for (int s = 0; s < 8; ++s) {
      const bf16x8 byf = *(const bf16x8*)(Byb + s * 32);
#pragma unroll
      for (int mt = 0; mt < 4; ++mt) {
        const bf16x8 afr = *(const bf16x8*)(hs + (mt * 16 + l16) * HS_STRIDE + kw + s * 32 + quad * 8);
        acc[mt] = __builtin_amdgcn_mfma_f32_16x16x32_bf16(afr, byf, acc[mt], 0, 0, 0);
      }
    }
    __syncthreads();   // hs reads done (only these waves read; others idle but sync below)
#pragma unroll
    for (int mt = 0; mt < 4; ++mt)
#pragma unroll
      for (int r = 0; r < 4; ++r)
        red[(size_t)(ks * 64 + mt * 16 + quad * 4 + r) * 68 + nsub * 16 + l16] = acc[mt][r];
  } else {
    __syncthreads();   // match the sync in the taken branch (wave-uniform nsub)
  }
  __syncthreads();

  {
    float o0 = by[i0 + ej], o1 = by[i0 + ej + 1];
#pragma unroll
    for (int w = 0; w < 4; ++w) {
      const float* rb = red + (size_t)(w * 64 + eb) * 68;
      o0 += rb[ej]; o1 += rb[ej + 1];
    }
    float2 ov; ov.x = o0; ov.y = o1;
    *(float2*)(out + (size_t)eb * 1024 + i0 + ej) = ov;
  }
}

extern "C" void kernel_launch(void* const* d_in, const int* in_sizes, int n_in,
                              void* d_out, int out_size, void* d_ws, size_t ws_size,
                              hipStream_t stream) {
  const float* x = (const float*)d_in[0];
  const float* Wxh = (const float*)d_in[1];
  const float* bh = (const float*)d_in[2];
  const float* Whh = (const float*)d_in[3];
  const float* Wxz = (const float*)d_in[4];
  const float* bz = (const float*)d_in[5];
  const float* Whz = (const float*)d_in[6];
  const float* Wy = (const float*)d_in[7];
  const float* by = (const float*)d_in[8];
  float* out = (float*)d_out;

  char* ws = (char*)d_ws;
  size_t off = 0;
  auto alloc = [&](size_t bytes) -> void* {
    void* p = ws + off;
    off += (bytes + 255) & ~(size_t)255;
    return p;
  };
  const size_t nX = (size_t)BB * TT * DD;  // 33554432
  unsigned short* xb = (unsigned short*)alloc(nX * 2);                  // x bf16
  unsigned short* Wcat = (unsigned short*)alloc((size_t)2048 * 1024 * 2);  // [Wxh;Wxz]
  unsigned short* WhzT = (unsigned short*)alloc((size_t)1024 * 1024 * 2);  // Whz^T
  unsigned short* Wrec = (unsigned short*)alloc((size_t)2048 * 1024 * 2);  // [Whh;Mz]
  unsigned short* Wyb = (unsigned short*)alloc((size_t)1024 * 1024 * 2);   // Wy bf16
  unsigned short* xhz = (unsigned short*)alloc((size_t)TT * BB * 2048 * 2);  // 128 MB
  unsigned short* hring = (unsigned short*)alloc((size_t)4 * SLOT_BYTES);   // 512 KB ring

  // ring init: data(-1)=h0=zeros lives in slot 3; slots 0..2 poisoned.
  hipMemsetAsync(hring, 0xFF, (size_t)3 * SLOT_BYTES, stream);
  hipMemsetAsync((char*)hring + (size_t)3 * SLOT_BYTES, 0, SLOT_BYTES, stream);

  // weight / input conversions
  k_f2b4<<<dim3((unsigned)(nX / 4 / 256)), 256, 0, stream>>>(x, xb, (int)(nX / 4));
  k_f2b4<<<dim3(1024), 256, 0, stream>>>(Wxh, Wcat, 262144);
  k_f2b4<<<dim3(1024), 256, 0, stream>>>(Wxz, Wcat + 1024 * 1024, 262144);
  k_f2b4<<<dim3(1024), 256, 0, stream>>>(Whh, Wrec, 262144);
  k_f2b4<<<dim3(1024), 256, 0, stream>>>(Wy, Wyb, 262144);
  k_transpose_bf16<<<dim3(32, 32), dim3(32, 8), 0, stream>>>(Whz, WhzT);

  // Mz = Wxz @ Whz  -> Wrec rows 1024..2047
  gemm_bt<1><<<dim3(8, 8), 256, 0, stream>>>(Wcat + 1024 * 1024, WhzT, nullptr, nullptr,
                                             Wrec + (size_t)1024 * 1024, 1024);
  // xhz = x @ [Wxh;Wxz]^T + [bh;bz], time-major
  gemm_bt<0><<<dim3(16, 256), 256, 0, stream>>>(xb, Wcat, bh, bz, xhz, 1024);

  // cooperative launch; opt in to 129 KB dynamic LDS (idempotent, capture-safe)
  hipFuncSetAttribute((const void*)scan_out_k,
                      hipFuncAttributeMaxDynamicSharedMemorySize, SCAN_LDS_BYTES);
  const unsigned short* xhz_c = xhz;
  const unsigned short* Wrec_c = Wrec;
  const unsigned short* Wyb_c = Wyb;
  const float* by_c = by;
  unsigned short* hring_c = hring;
  void* kargs[] = {(void*)&xhz_c, (void*)&Wrec_c, (void*)&Wyb_c, (void*)&by_c,
                   (void*)&hring_c, (void*)&out};
  hipLaunchCooperativeKernel((void*)scan_out_k, dim3(SCAN_BLOCKS), dim3(1024),
                             kargs, SCAN_LDS_BYTES, stream);
}